// Round 9
// baseline (362.848 us; speedup 1.0000x reference)
//
#include <hip/hip_runtime.h>
#include <math.h>

#define NB    2048
#define NSEG  20
#define MAXIT 48
// LDS chunk layout: one 32-k chunk = 4 octet-blocks of BLKS shorts.
// BLKS = 128 data shorts (16 cols x 8 k) + 8 pad shorts = 136.
// cols 0..7 = bf16-hi of elems 0..7, cols 8..15 = bf16-lo of elems 0..7.
// Bank math: BLKS*2B = 272B = 68 dwords == 4 (mod 32); chunk stride 544*2/4 = 272 == 16 (mod 32).
#define CH    544
#define BLKS  136

typedef __attribute__((ext_vector_type(8))) short bf8_t;
typedef __attribute__((ext_vector_type(4))) float f32x4;

#define cA21 ((float)0.161)
#define cA31 ((float)-0.008480655492356989)
#define cA32 ((float)0.335480655492357)
#define cA41 ((float)2.8971530571054935)
#define cA42 ((float)-6.359448489975075)
#define cA43 ((float)4.3622954328695815)
#define cA51 ((float)5.325864828439257)
#define cA52 ((float)-11.748883564062828)
#define cA53 ((float)7.4955393428898365)
#define cA54 ((float)-0.09249506636175525)
#define cA61 ((float)5.86145544294642)
#define cA62 ((float)-12.92096931784711)
#define cA63 ((float)8.159367898576159)
#define cA64 ((float)-0.071584973281401)
#define cA65 ((float)-0.028269050394068383)
#define cB1  ((float)0.09646076681806523)
#define cB2  ((float)0.01)
#define cB3  ((float)0.4798896504144996)
#define cB4  ((float)1.379008574103742)
#define cB5  ((float)-3.290069515436081)
#define cB6  ((float)2.324710524099774)
#define cE1  ((float)-0.001780011052225777)
#define cE2  ((float)-0.0008164344596567469)
#define cE3  ((float)0.007880878010261995)
#define cE4  ((float)-0.1447110071732629)
#define cE5  ((float)0.5823571654525552)
#define cE6  ((float)-0.45808210592918697)
#define cE7  ((float)0.015151515151515152)

__device__ __forceinline__ void split2(float x, short &hi, short &lo) {
    // x ~= bf16(hi) + bf16(lo), truncation-based (x - hi is exact in fp32)
    unsigned u = __float_as_uint(x);
    hi = (short)(u >> 16);
    float r = x - __uint_as_float(u & 0xFFFF0000u);
    lo = (short)(__float_as_uint(r) >> 16);
}

__device__ __forceinline__ float softplus_f(float x) {
    float t = exp2f(-fabsf(x) * 1.442695040888963f);
    return fmaxf(x, 0.0f) + log2f(1.0f + t) * 0.6931471805599453f;
}

__device__ __forceinline__ unsigned pk(short a, short b) {
    return ((unsigned)(unsigned short)a) | (((unsigned)(unsigned short)b) << 16);
}

// x + x[lane^8] within each 16-lane row: DPP row_ror:8 (0x128).  Pure VALU.
// NOTE: apply BEFORE any esel-dependent register select (round-4 lesson).
__device__ __forceinline__ float fold8(float x) {
    int r = __builtin_amdgcn_update_dpp(__float_as_int(x), __float_as_int(x),
                                        0x128, 0xF, 0xF, false);
    return x + __int_as_float(r);
}

// 512 threads = 8 waves; block processes 8 elements in lockstep.
// z-space (round-8 math, new schedule): waves 0-3 = k-waves (W3 gemm -> k,
// y-state, error); waves 4-7 = u-waves (M=W1*W3 gemm over TWO 16-row tiles
// -> all 128 u-dims at 4/lane, z-state, RK combo, softplus, h1B write).
// Per eval: PhA (all: W2 h1B->h2B) bar; PhB (k-gemm || u-gemm+combo+sp+write)
// bar.  Each SIMD pairs one k-wave with one u-wave -> short k-chain hides
// under the long u-chain (role-diverse phases: round-6 overlap mechanism
// without per-element issue-work increase).  u/k values bit-identical to r8.
// Frag-layout (16x16x32 bf16): A[m=lane&15][k=32c+8*quad+jj]; B[k][n=lane&15];
// C/D: col=lane&15, row=4*quad+reg  (m89-verified).
__global__ __launch_bounds__(512)
void ode_kernel(const float* __restrict__ history,
                const float* __restrict__ W1, const float* __restrict__ b1,
                const float* __restrict__ W2, const float* __restrict__ b2,
                const float* __restrict__ W3, const float* __restrict__ b3,
                float* __restrict__ out)
{
    __shared__ alignas(16) short h1B[4 * CH];
    __shared__ alignas(16) short h2B[4 * CH];
    __shared__ float rrP[32];   // [k-wave][elem] error-norm partials

    const int tid  = threadIdx.x;
    const int wave = tid >> 6, lane = tid & 63;
    const int quad = lane >> 4, col = lane & 15;
    const int w4   = wave & 3;
    const bool isU = wave >= 4;
    const int esel = col >> 3;
    const int e    = col & 7;
    const int jb   = 16 * wave + 4 * quad;           // PhA epi row base (0..127)
    const int j0   = jb + 2 * esel;                  // PhA epi rows
    const int j0A  = 16 * w4 + 4 * quad + 2 * esel;  // tile-A rows / k-wave dims
    const int j0B  = 64 + j0A;                       // tile-B rows (u-waves)
    const size_t elemIdx = (size_t)(blockIdx.x * 8 + e);

    auto bidx = [&](int j) { return (j >> 5) * CH + ((j >> 3) & 3) * BLKS + e * 8 + (j & 7); };
    const int zi   = bidx(j0);
    const int ziA  = bidx(j0A);
    const int ziB  = bidx(j0B);
    const int boff = quad * BLKS + col * 8;

    // ---- W2 frags (all waves, rows 16w+col) ----
    bf8_t A2h[4], A2l[4];
#pragma unroll
    for (int c = 0; c < 4; ++c) {
        const float* p = W2 + (size_t)(16 * wave + col) * 128 + 32 * c + 8 * quad;
        bf8_t h, l;
#pragma unroll
        for (int j = 0; j < 8; ++j) { short hs, ls; split2(p[j], hs, ls); h[j] = hs; l[j] = ls; }
        A2h[c] = h; A2l[c] = l;
    }
    const f32x4 b2f = *(const f32x4*)(b2 + jb);

    // ---- role-specific frags & state vectors ----
    bf8_t A3h[4], A3l[4];                       // k-waves: W3 rows 16w+col
    bf8_t MhA[4], MlA[4], MhB[4], MlB[4];       // u-waves: M rows 16w4+col, 64+16w4+col
    float b3v0 = 0.f, b3v1 = 0.f, ys0 = 0.f, ys1 = 0.f;
    f32x4 zy  = {0.f, 0.f, 0.f, 0.f};
    f32x4 ccv = {0.f, 0.f, 0.f, 0.f};
    {
        bf8_t z = {0, 0, 0, 0, 0, 0, 0, 0};
#pragma unroll
        for (int c = 0; c < 4; ++c) { A3h[c] = z; A3l[c] = z; MhA[c] = z; MlA[c] = z; MhB[c] = z; MlB[c] = z; }
    }
    if (!isU) {
#pragma unroll
        for (int c = 0; c < 4; ++c) {
            const float* p = W3 + (size_t)(16 * wave + col) * 128 + 32 * c + 8 * quad;
            bf8_t h, l;
#pragma unroll
            for (int j = 0; j < 8; ++j) { short hs, ls; split2(p[j], hs, ls); h[j] = hs; l[j] = ls; }
            A3h[c] = h; A3l[c] = l;
        }
        b3v0 = b3[j0A]; b3v1 = b3[j0A + 1];
    } else {
        // ---- M = W1*W3 (two 16-row tiles), 64 entries/lane ----
#pragma unroll 1
        for (int tt = 0; tt < 2; ++tt) {
            float accM[4][8];
#pragma unroll
            for (int cc = 0; cc < 4; ++cc)
#pragma unroll
                for (int j = 0; j < 8; ++j) accM[cc][j] = 0.f;
            const float* w1r = W1 + (size_t)(64 * tt + 16 * w4 + col) * 64;
#pragma unroll 2
            for (int d = 0; d < 64; ++d) {
                float wv = w1r[d];
                const float* w3r = W3 + (size_t)d * 128 + 8 * quad;
#pragma unroll
                for (int cc = 0; cc < 4; ++cc) {
                    f32x4 va = *(const f32x4*)(w3r + 32 * cc);
                    f32x4 vb = *(const f32x4*)(w3r + 32 * cc + 4);
#pragma unroll
                    for (int j = 0; j < 4; ++j) {
                        accM[cc][j]     = fmaf(wv, va[j], accM[cc][j]);
                        accM[cc][4 + j] = fmaf(wv, vb[j], accM[cc][4 + j]);
                    }
                }
            }
#pragma unroll
            for (int cc = 0; cc < 4; ++cc) {
                bf8_t hh, ll;
#pragma unroll
                for (int j = 0; j < 8; ++j) { short hs, ls; split2(accM[cc][j], hs, ls); hh[j] = hs; ll[j] = ls; }
                if (tt == 0) { MhA[cc] = hh; MlA[cc] = ll; }
                else         { MhB[cc] = hh; MlB[cc] = ll; }
            }
        }
    }

    // returns per-reg sum of the two accumulator chains (pre-fold)
    auto gemm = [&](const bf8_t* Ah, const bf8_t* Al, const short* Bc, int nch) -> f32x4 {
        f32x4 a0 = {0.f, 0.f, 0.f, 0.f}, a1 = a0;
#pragma unroll
        for (int c = 0; c < nch; ++c) {
            bf8_t b = *(const bf8_t*)(Bc + c * CH + boff);
            a0 = __builtin_amdgcn_mfma_f32_16x16x32_bf16(Ah[c], b, a0, 0, 0, 0);
            a1 = __builtin_amdgcn_mfma_f32_16x16x32_bf16(Al[c], b, a1, 0, 0, 0);
        }
        f32x4 s;
#pragma unroll
        for (int r = 0; r < 4; ++r) s[r] = a0[r] + a1[r];
        return s;
    };

    // PhA epilogue (all waves): fold ALL regs first, select after (round-4 lesson)
    auto epi = [&](f32x4 s, f32x4 bias, short* Bn) {
        float t0 = fold8(s[0]) + bias[0];
        float t1 = fold8(s[1]) + bias[1];
        float t2 = fold8(s[2]) + bias[2];
        float t3 = fold8(s[3]) + bias[3];
        float x0 = esel ? t2 : t0;
        float x1 = esel ? t3 : t1;
        float p0 = softplus_f(x0), p1 = softplus_f(x1);
        short h0s, l0s, h1s, l1s;
        split2(p0, h0s, l0s);
        split2(p1, h1s, l1s);
        *(unsigned*)(Bn + zi)      = pk(h0s, h1s);
        *(unsigned*)(Bn + zi + 64) = pk(l0s, l1s);
    };

    // u-wave: softplus + split + write all 4 z-dims to h1B
    auto spw = [&](f32x4 zs) {
        float p0 = softplus_f(zs[0]), p1 = softplus_f(zs[1]);
        float p2 = softplus_f(zs[2]), p3 = softplus_f(zs[3]);
        short ha, la, hb, lb;
        split2(p0, ha, la); split2(p1, hb, lb);
        *(unsigned*)(h1B + ziA)      = pk(ha, hb);
        *(unsigned*)(h1B + ziA + 64) = pk(la, lb);
        split2(p2, ha, la); split2(p3, hb, lb);
        *(unsigned*)(h1B + ziB)      = pk(ha, hb);
        *(unsigned*)(h1B + ziB + 64) = pk(la, lb);
    };

    // PhB: k-waves -> (ka,kb); u-waves -> uo (4 dims)
    auto phB = [&](f32x4 &uo, float &ka, float &kb) {
        if (!isU) {
            f32x4 z = {0.f, 0.f, 0.f, 0.f};
            f32x4 w0 = z, w1 = z;
#pragma unroll
            for (int c = 0; c < 4; ++c) {
                bf8_t b = *(const bf8_t*)(h2B + c * CH + boff);
                w0 = __builtin_amdgcn_mfma_f32_16x16x32_bf16(A3h[c], b, w0, 0, 0, 0);
                w1 = __builtin_amdgcn_mfma_f32_16x16x32_bf16(A3l[c], b, w1, 0, 0, 0);
            }
            float g0 = fold8(w0[0] + w1[0]);
            float g1 = fold8(w0[1] + w1[1]);
            float g2 = fold8(w0[2] + w1[2]);
            float g3 = fold8(w0[3] + w1[3]);
            ka = (esel ? g2 : g0) + b3v0;
            kb = (esel ? g3 : g1) + b3v1;
        } else {
            f32x4 z = {0.f, 0.f, 0.f, 0.f};
            f32x4 aA0 = z, aA1 = z, aB0 = z, aB1 = z;
#pragma unroll
            for (int c = 0; c < 4; ++c) {
                bf8_t b = *(const bf8_t*)(h2B + c * CH + boff);
                aA0 = __builtin_amdgcn_mfma_f32_16x16x32_bf16(MhA[c], b, aA0, 0, 0, 0);
                aA1 = __builtin_amdgcn_mfma_f32_16x16x32_bf16(MlA[c], b, aA1, 0, 0, 0);
                aB0 = __builtin_amdgcn_mfma_f32_16x16x32_bf16(MhB[c], b, aB0, 0, 0, 0);
                aB1 = __builtin_amdgcn_mfma_f32_16x16x32_bf16(MlB[c], b, aB1, 0, 0, 0);
            }
            float fA0 = fold8(aA0[0] + aA1[0]);
            float fA1 = fold8(aA0[1] + aA1[1]);
            float fA2 = fold8(aA0[2] + aA1[2]);
            float fA3 = fold8(aA0[3] + aA1[3]);
            float fB0 = fold8(aB0[0] + aB1[0]);
            float fB1 = fold8(aB0[1] + aB1[1]);
            float fB2 = fold8(aB0[2] + aB1[2]);
            float fB3 = fold8(aB0[3] + aB1[3]);
            uo[0] = (esel ? fA2 : fA0) + ccv[0];
            uo[1] = (esel ? fA3 : fA1) + ccv[1];
            uo[2] = (esel ? fB2 : fB0) + ccv[2];
            uo[3] = (esel ? fB3 : fB1) + ccv[3];
        }
    };

    // ---- init: stage y0/b3, W1-gemms -> zy (=W1*y0+b1) and cc (=W1*b3) ----
    if (!isU) {
        float2 yy = *(const float2*)(history + (elemIdx * 15 + 14) * 64 + j0A);
        ys0 = yy.x; ys1 = yy.y;
        short ha, la, hb, lb;
        split2(ys0, ha, la); split2(ys1, hb, lb);
        *(unsigned*)(h1B + ziA)      = pk(ha, hb);
        *(unsigned*)(h1B + ziA + 64) = pk(la, lb);
        split2(b3v0, ha, la); split2(b3v1, hb, lb);
        *(unsigned*)(h2B + ziA)      = pk(ha, hb);
        *(unsigned*)(h2B + ziA + 64) = pk(la, lb);
    }
    __syncthreads();
    if (isU) {
        bf8_t W1h[2], W1l[2];
#pragma unroll 1
        for (int tt = 0; tt < 2; ++tt) {
            const int jt = tt ? j0B : j0A;
#pragma unroll
            for (int c = 0; c < 2; ++c) {
                const float* p = W1 + (size_t)(64 * tt + 16 * w4 + col) * 64 + 32 * c + 8 * quad;
                bf8_t h, l;
#pragma unroll
                for (int j = 0; j < 8; ++j) { short hs, ls; split2(p[j], hs, ls); h[j] = hs; l[j] = ls; }
                W1h[c] = h; W1l[c] = l;
            }
            f32x4 sz = gemm(W1h, W1l, h1B, 2);
            f32x4 sc = gemm(W1h, W1l, h2B, 2);
            float f0 = fold8(sz[0]), f1 = fold8(sz[1]), f2 = fold8(sz[2]), f3 = fold8(sz[3]);
            float g0 = fold8(sc[0]), g1 = fold8(sc[1]), g2 = fold8(sc[2]), g3 = fold8(sc[3]);
            if (tt == 0) {
                zy[0] = (esel ? f2 : f0) + b1[jt];
                zy[1] = (esel ? f3 : f1) + b1[jt + 1];
                ccv[0] = esel ? g2 : g0;
                ccv[1] = esel ? g3 : g1;
            } else {
                zy[2] = (esel ? f2 : f0) + b1[jt];
                zy[3] = (esel ? f3 : f1) + b1[jt + 1];
                ccv[2] = esel ? g2 : g0;
                ccv[3] = esel ? g3 : g1;
            }
        }
    }
    __syncthreads();                 // init gemms consumed h1B/h2B
    if (isU) spw(zy);                // z1 = zy -> h1 = sp(z1)
    __syncthreads();

    // ---- state ----
    float dt = 0.1f;
    f32x4 u1 = {0.f, 0.f, 0.f, 0.f}, u2 = u1, u3 = u1, u4 = u1, u5 = u1, u6 = u1, u7 = u1;
    float k1a = 0.f, k1b = 0.f, k2a = 0.f, k2b = 0.f, k3a = 0.f, k3b = 0.f;
    float k4a = 0.f, k4b = 0.f, k5a = 0.f, k5b = 0.f, k6a = 0.f, k6b = 0.f;
    float k7a = 0.f, k7b = 0.f;

    // initial eval: k1 (k-waves), u1 (u-waves)   [FSAL thereafter]
    {
        f32x4 s2 = gemm(A2h, A2l, h1B, 4);
        epi(s2, b2f, h2B);
        __syncthreads();
        phB(u1, k1a, k1b);
    }

#pragma unroll 1
    for (int seg = 1; seg <= NSEG; ++seg) {
        const float tEnd = (float)seg;
        float t = tEnd - 1.0f;
        bool done = false;

#pragma unroll 1
        for (int it = 0; it < MAXIT; ++it) {
            const float dt_c = fminf(dt, tEnd - t);
            const float h = dt_c;
            f32x4 zy5 = {0.f, 0.f, 0.f, 0.f};
            float y50 = 0.f, y51 = 0.f;

            if (isU) {                       // z2 = zy + h*A21*u1
                f32x4 zn;
#pragma unroll
                for (int r = 0; r < 4; ++r) zn[r] = fmaf(h, cA21 * u1[r], zy[r]);
                spw(zn);
            }
            __syncthreads();                 // (A) h1B ready

#pragma unroll 1
            for (int st = 2; st <= 7; ++st) {
                {   // PhA: W2 gemm
                    f32x4 s2 = gemm(A2h, A2l, h1B, 4);
                    epi(s2, b2f, h2B);
                }
                __syncthreads();             // (B) h2B ready
                f32x4 uo = {0.f, 0.f, 0.f, 0.f};
                float ka = 0.f, kb = 0.f;
                phB(uo, ka, kb);
                if (isU) {
                    switch (st) {
                        case 2: u2 = uo; break;
                        case 3: u3 = uo; break;
                        case 4: u4 = uo; break;
                        case 5: u5 = uo; break;
                        case 6: u6 = uo; break;
                        default: u7 = uo; break;
                    }
                } else {
                    switch (st) {
                        case 2: k2a = ka; k2b = kb; break;
                        case 3: k3a = ka; k3b = kb; break;
                        case 4: k4a = ka; k4b = kb; break;
                        case 5: k5a = ka; k5b = kb; break;
                        case 6: k6a = ka; k6b = kb; break;
                        default: k7a = ka; k7b = kb; break;
                    }
                }
                if (st < 7) {
                    if (isU) {               // combo z_{st+1}, sp, write h1B
                        f32x4 zn;
#pragma unroll
                        for (int r = 0; r < 4; ++r) {
                            float sv;
                            switch (st) {
                                case 2: sv = fmaf(cA31, u1[r], cA32 * u2[r]); break;
                                case 3: sv = fmaf(cA41, u1[r], fmaf(cA42, u2[r], cA43 * u3[r])); break;
                                case 4: sv = fmaf(cA51, u1[r], fmaf(cA52, u2[r], fmaf(cA53, u3[r], cA54 * u4[r]))); break;
                                case 5: sv = fmaf(cA61, u1[r], fmaf(cA62, u2[r], fmaf(cA63, u3[r], fmaf(cA64, u4[r], cA65 * u5[r])))); break;
                                default: sv = fmaf(cB1, u1[r], fmaf(cB2, u2[r], fmaf(cB3, u3[r], fmaf(cB4, u4[r], fmaf(cB5, u5[r], cB6 * u6[r]))))); break;
                            }
                            zn[r] = fmaf(h, sv, zy[r]);
                        }
                        if (st == 6) zy5 = zn;   // z7 = z-mirror of y5
                        spw(zn);
                    }
                    __syncthreads();         // (A') h1B ready for next PhA
                }
            }

            // error norm (k-waves): y5 combo + E-combo, 2 dims/lane
            float rr2 = 0.f;
            if (!isU) {
                float ta = fmaf(cB1, k1a, fmaf(cB2, k2a, fmaf(cB3, k3a, fmaf(cB4, k4a, fmaf(cB5, k5a, cB6 * k6a)))));
                float tb = fmaf(cB1, k1b, fmaf(cB2, k2b, fmaf(cB3, k3b, fmaf(cB4, k4b, fmaf(cB5, k5b, cB6 * k6b)))));
                y50 = fmaf(h, ta, ys0);
                y51 = fmaf(h, tb, ys1);
                float es0 = fmaf(cE1, k1a, fmaf(cE2, k2a, fmaf(cE3, k3a,
                            fmaf(cE4, k4a, fmaf(cE5, k5a, fmaf(cE6, k6a, cE7 * k7a))))));
                float es1 = fmaf(cE1, k1b, fmaf(cE2, k2b, fmaf(cE3, k3b,
                            fmaf(cE4, k4b, fmaf(cE5, k5b, fmaf(cE6, k6b, cE7 * k7b))))));
                float err0 = h * es0, err1 = h * es1;
                float sc0 = fmaf(1e-3f, fmaxf(fabsf(ys0), fabsf(y50)), 1e-6f);
                float sc1 = fmaf(1e-3f, fmaxf(fabsf(ys1), fabsf(y51)), 1e-6f);
                float r0 = err0 / sc0, r1 = err1 / sc1;
                rr2 = fmaf(r0, r0, r1 * r1);
            }
            rr2 += __shfl_xor(rr2, 16, 64);   // sum quad bit0
            rr2 += __shfl_xor(rr2, 32, 64);   // sum quad bit1
            rr2 = fold8(rr2);                 // sum esel halves (symmetric, no select)
            if (!isU && lane < 8) rrP[wave * 8 + lane] = rr2;  // lane = elem
            __syncthreads();                  // (C)
            float rs = ((rrP[e] + rrP[8 + e]) + rrP[16 + e]) + rrP[24 + e];
            float en = sqrtf(rs * (1.0f / 64.0f));

            bool accept = (en <= 1.0f) && !done;
            float fac = 0.9f * exp2f(-0.2f * log2f(fmaxf(en, 1e-10f)));
            fac = fminf(fmaxf(fac, 0.2f), 10.0f);

            if (accept) {
                t += dt_c;
                if (!isU) { ys0 = y50; ys1 = y51; k1a = k7a; k1b = k7b; }  // FSAL
                else      { zy = zy5; u1 = u7; }
            }
            if (!done) dt = dt_c * fac;
            done = done || (t >= tEnd - 1e-8f);
            if (__all(done)) break;
        }

        if (!isU) {
            float2 yy; yy.x = ys0; yy.y = ys1;
            *(float2*)(out + (elemIdx * NSEG + (seg - 1)) * 64 + j0A) = yy;
        }
    }
}

extern "C" void kernel_launch(void* const* d_in, const int* in_sizes, int n_in,
                              void* d_out, int out_size, void* d_ws, size_t ws_size,
                              hipStream_t stream) {
    const float* history = (const float*)d_in[0];
    const float* W1 = (const float*)d_in[1];
    const float* b1 = (const float*)d_in[2];
    const float* W2 = (const float*)d_in[3];
    const float* b2 = (const float*)d_in[4];
    const float* W3 = (const float*)d_in[5];
    const float* b3 = (const float*)d_in[6];
    float* out = (float*)d_out;

    ode_kernel<<<dim3(NB / 8), dim3(512), 0, stream>>>(history, W1, b1, W2, b2, W3, b3, out);
}

// Round 10
// 278.109 us; speedup vs baseline: 1.3047x; 1.3047x over previous
//
#include <hip/hip_runtime.h>
#include <math.h>

#define NB    2048
#define NSEG  20
#define MAXIT 48
// LDS chunk layout: one 32-k chunk = 4 octet-blocks of BLKS shorts.
// BLKS = 128 data shorts (16 cols x 8 k) + 8 pad shorts = 136.
// cols 0..7 = bf16-hi of elems 0..7, cols 8..15 = bf16-lo of elems 0..7.
// Bank math: BLKS*2B = 272B = 68 dwords == 4 (mod 32); chunk stride 544*2/4 = 272 == 16 (mod 32).
#define CH    544
#define BLKS  136

typedef __attribute__((ext_vector_type(8))) short bf8_t;
typedef __attribute__((ext_vector_type(4))) float f32x4;

#define cA21 ((float)0.161)
#define cA31 ((float)-0.008480655492356989)
#define cA32 ((float)0.335480655492357)
#define cA41 ((float)2.8971530571054935)
#define cA42 ((float)-6.359448489975075)
#define cA43 ((float)4.3622954328695815)
#define cA51 ((float)5.325864828439257)
#define cA52 ((float)-11.748883564062828)
#define cA53 ((float)7.4955393428898365)
#define cA54 ((float)-0.09249506636175525)
#define cA61 ((float)5.86145544294642)
#define cA62 ((float)-12.92096931784711)
#define cA63 ((float)8.159367898576159)
#define cA64 ((float)-0.071584973281401)
#define cA65 ((float)-0.028269050394068383)
#define cB1  ((float)0.09646076681806523)
#define cB2  ((float)0.01)
#define cB3  ((float)0.4798896504144996)
#define cB4  ((float)1.379008574103742)
#define cB5  ((float)-3.290069515436081)
#define cB6  ((float)2.324710524099774)
#define cE1  ((float)-0.001780011052225777)
#define cE2  ((float)-0.0008164344596567469)
#define cE3  ((float)0.007880878010261995)
#define cE4  ((float)-0.1447110071732629)
#define cE5  ((float)0.5823571654525552)
#define cE6  ((float)-0.45808210592918697)
#define cE7  ((float)0.015151515151515152)

__device__ __forceinline__ void split2(float x, short &hi, short &lo) {
    // x ~= bf16(hi) + bf16(lo), truncation-based (x - hi is exact in fp32)
    unsigned u = __float_as_uint(x);
    hi = (short)(u >> 16);
    float r = x - __uint_as_float(u & 0xFFFF0000u);
    lo = (short)(__float_as_uint(r) >> 16);
}

__device__ __forceinline__ float softplus_f(float x) {
    float t = exp2f(-fabsf(x) * 1.442695040888963f);
    return fmaxf(x, 0.0f) + log2f(1.0f + t) * 0.6931471805599453f;
}

__device__ __forceinline__ unsigned pk(short a, short b) {
    return ((unsigned)(unsigned short)a) | (((unsigned)(unsigned short)b) << 16);
}

// x + x[lane^8] within each 16-lane row: DPP row_ror:8 (0x128).  Pure VALU.
// NOTE: apply BEFORE any esel-dependent register select (round-4 lesson).
__device__ __forceinline__ float fold8(float x) {
    int r = __builtin_amdgcn_update_dpp(__float_as_int(x), __float_as_int(x),
                                        0x128, 0xF, 0xF, false);
    return x + __int_as_float(r);
}

// 512 threads = 8 waves; block processes 8 elements in eval-lockstep.
// ASYNC CONTROLLER (round 10): each element advances through its OWN segment
// schedule (segE, t, dt per element; crossing writes its output row and moves
// to the next segment immediately).  The block loops until all 8 elements
// finish all 20 segments.  Per-element trajectories are bit-identical to the
// lockstep version (eval math is element-local); only iteration packing
// changes: sum_seg(max8 steps) -> max8(sum_seg steps), ~20% fewer evals.
// All 64-lane controller replicas for elem col&7 are deterministic (en from
// shared rrP), so __all() is block-consistent.
// Weights live in per-lane MFMA A-fragments (bf16 hi/lo) for the whole kernel.
// Acts ping-pong through LDS in MFMA B-fragment layout with hi/lo packed into
// the 16 columns: col e = hi(elem e), col e+8 = lo(elem e).  Two MFMAs/chunk.
// RK state in MFMA D-layout on waves 0-3 (2 dims/lane); L3 output consumed
// in-register.  Waves 4-7 are pure GEMM workers (deterministic replicas).
// Frag-layout (16x16x32 bf16): A[m=lane&15][k=32c+8*quad+jj]; B[k][n=lane&15];
// C/D: col=lane&15, row=4*quad+reg  (m89-verified).
__global__ __launch_bounds__(512)
void ode_kernel(const float* __restrict__ history,
                const float* __restrict__ W1, const float* __restrict__ b1,
                const float* __restrict__ W2, const float* __restrict__ b2,
                const float* __restrict__ W3, const float* __restrict__ b3,
                float* __restrict__ out)
{
    __shared__ alignas(16) short argB[2 * CH];
    __shared__ alignas(16) short h1B[4 * CH];
    __shared__ alignas(16) short h2B[4 * CH];
    __shared__ float rrP[32];   // [wave<4][elem] error-norm partials

    const int tid  = threadIdx.x;
    const int wave = tid >> 6, lane = tid & 63;
    const int quad = lane >> 4, col = lane & 15;
    const int jb   = 16 * wave + 4 * quad;       // this lane's D-row base (j)

    // ---- preload weight A-fragments (bf16 hi/lo) ----
    bf8_t A1h[2], A1l[2], A2h[4], A2l[4], A3h[4], A3l[4];
#pragma unroll
    for (int c = 0; c < 2; ++c) {
        const float* p = W1 + (size_t)(16 * wave + col) * 64 + 32 * c + 8 * quad;
        bf8_t h, l;
#pragma unroll
        for (int j = 0; j < 8; ++j) { short hs, ls; split2(p[j], hs, ls); h[j] = hs; l[j] = ls; }
        A1h[c] = h; A1l[c] = l;
    }
#pragma unroll
    for (int c = 0; c < 4; ++c) {
        const float* p = W2 + (size_t)(16 * wave + col) * 128 + 32 * c + 8 * quad;
        bf8_t h, l;
#pragma unroll
        for (int j = 0; j < 8; ++j) { short hs, ls; split2(p[j], hs, ls); h[j] = hs; l[j] = ls; }
        A2h[c] = h; A2l[c] = l;
    }
    // state mapping (waves 0-3): esel splits the 4 D-rows into two 2-row halves
    const int esel = col >> 3;
    const int e    = col & 7;
    const int d0   = 16 * wave + 4 * quad + 2 * esel;   // meaningful for wave<4
    const size_t elemIdx = (size_t)(blockIdx.x * 8 + e);

    float b3v0 = 0.f, b3v1 = 0.f;
    if (wave < 4) {
#pragma unroll
        for (int c = 0; c < 4; ++c) {
            const float* p = W3 + (size_t)(16 * wave + col) * 128 + 32 * c + 8 * quad;
            bf8_t h, l;
#pragma unroll
            for (int j = 0; j < 8; ++j) { short hs, ls; split2(p[j], hs, ls); h[j] = hs; l[j] = ls; }
            A3h[c] = h; A3l[c] = l;
        }
        b3v0 = b3[d0]; b3v1 = b3[d0 + 1];
    } else {
        bf8_t z = {0, 0, 0, 0, 0, 0, 0, 0};
#pragma unroll
        for (int c = 0; c < 4; ++c) { A3h[c] = z; A3l[c] = z; }
    }
    const f32x4 b1f = *(const f32x4*)(b1 + jb);
    const f32x4 b2f = *(const f32x4*)(b2 + jb);

    // arg-write index (waves 0-3): same formula as epidx, rows = dims 0..63
    const int ai = (d0 >> 5) * CH + ((d0 >> 3) & 3) * BLKS + e * 8 + (d0 & 7);

    // epilogue mapping: lane (quad, col) handles elem col&7, rows j0, j0+1
    const int j0    = 16 * wave + 4 * quad + 2 * esel;
    const int epidx = (j0 >> 5) * CH + ((j0 >> 3) & 3) * BLKS + e * 8 + (j0 & 7);

    // B-read offset: full 16 distinct columns (8 hi + 8 lo)
    const int boff = quad * BLKS + col * 8;

    // returns per-reg sum of the two accumulator chains (pre-fold)
    auto gemm = [&](const bf8_t* Ah, const bf8_t* Al, const short* Bc, int nch) -> f32x4 {
        f32x4 a0 = {0.f, 0.f, 0.f, 0.f}, a1 = a0;
#pragma unroll
        for (int c = 0; c < nch; ++c) {
            bf8_t b = *(const bf8_t*)(Bc + c * CH + boff);
            a0 = __builtin_amdgcn_mfma_f32_16x16x32_bf16(Ah[c], b, a0, 0, 0, 0);
            a1 = __builtin_amdgcn_mfma_f32_16x16x32_bf16(Al[c], b, a1, 0, 0, 0);
        }
        f32x4 s;
#pragma unroll
        for (int r = 0; r < 4; ++r) s[r] = a0[r] + a1[r];
        return s;
    };

    // all-lane epilogue: fold hi/lo columns (ALL regs, then select), softplus,
    // split back to hi/lo bf16 and store both column groups.
    auto epi = [&](f32x4 s, f32x4 bias, short* Bn) {
        float t0 = fold8(s[0]) + bias[0];
        float t1 = fold8(s[1]) + bias[1];
        float t2 = fold8(s[2]) + bias[2];
        float t3 = fold8(s[3]) + bias[3];
        float x0 = esel ? t2 : t0;
        float x1 = esel ? t3 : t1;
        float p0 = softplus_f(x0), p1 = softplus_f(x1);
        short h0s, l0s, h1s, l1s;
        split2(p0, h0s, l0s);
        split2(p1, h1s, l1s);
        *(unsigned*)(Bn + epidx)      = pk(h0s, h1s);
        *(unsigned*)(Bn + epidx + 64) = pk(l0s, l1s);
    };

    // one full MLP eval; args must be in argB.  L3 result (this lane's 2 dims)
    // returned in kv0/kv1 for waves 0-3.  3 barriers, no trailing one.
    auto eval = [&](float &kv0, float &kv1) {
        __syncthreads();
        f32x4 s1 = gemm(A1h, A1l, argB, 2);
        epi(s1, b1f, h1B);
        __syncthreads();
        f32x4 s2 = gemm(A2h, A2l, h1B, 4);
        epi(s2, b2f, h2B);
        __syncthreads();
        if (wave < 4) {
            f32x4 s3 = gemm(A3h, A3l, h2B, 4);
            // fold FIRST (both lane halves fold the same register), select after
            float f0 = fold8(s3[0]);
            float f1 = fold8(s3[1]);
            float f2 = fold8(s3[2]);
            float f3 = fold8(s3[3]);
            kv0 = (esel ? f2 : f0) + b3v0;
            kv1 = (esel ? f3 : f1) + b3v1;
        }
    };

    auto argw = [&](float a0, float a1) {
        short h0s, l0s, h1s, l1s;
        split2(a0, h0s, l0s); split2(a1, h1s, l1s);
        *(unsigned*)(argB + ai)      = pk(h0s, h1s);
        *(unsigned*)(argB + ai + 64) = pk(l0s, l1s);
    };

    // ---- state (waves 0-3, D-layout): 2 dims per lane ----
    float y0 = 0.f, y1 = 0.f;
    float k1a = 0.f, k1b = 0.f, k2a, k2b, k3a, k3b, k4a, k4b, k5a, k5b, k6a, k6b;

    // ---- async per-element controller (replicated on every lane) ----
    float dt   = 0.1f;
    float t    = 0.0f;
    int   segE = 1;           // current target segment (tEnd = segE)
    bool  aliveE = true;      // segE <= NSEG

    // initial k1 = f(y)  (FSAL thereafter)
    if (wave < 4) {
        float2 yy = *(const float2*)(history + (elemIdx * 15 + 14) * 64 + d0);
        y0 = yy.x; y1 = yy.y;
        argw(y0, y1);
    }
    eval(k1a, k1b);

#pragma unroll 1
    for (int iter = 0; iter < NSEG * MAXIT; ++iter) {
        const float tEnd = (float)segE;
        const float dt_c = fminf(dt, tEnd - t);
        const float h = dt_c;
        float y50 = 0.f, y51 = 0.f, k7a = 0.f, k7b = 0.f;

#pragma unroll 1
        for (int st = 2; st <= 7; ++st) {
            if (wave < 4) {
                float sum0, sum1;
                switch (st) {
                    case 2: sum0 = cA21 * k1a;
                            sum1 = cA21 * k1b; break;
                    case 3: sum0 = fmaf(cA31, k1a, cA32 * k2a);
                            sum1 = fmaf(cA31, k1b, cA32 * k2b); break;
                    case 4: sum0 = fmaf(cA41, k1a, fmaf(cA42, k2a, cA43 * k3a));
                            sum1 = fmaf(cA41, k1b, fmaf(cA42, k2b, cA43 * k3b)); break;
                    case 5: sum0 = fmaf(cA51, k1a, fmaf(cA52, k2a, fmaf(cA53, k3a, cA54 * k4a)));
                            sum1 = fmaf(cA51, k1b, fmaf(cA52, k2b, fmaf(cA53, k3b, cA54 * k4b))); break;
                    case 6: sum0 = fmaf(cA61, k1a, fmaf(cA62, k2a, fmaf(cA63, k3a, fmaf(cA64, k4a, cA65 * k5a))));
                            sum1 = fmaf(cA61, k1b, fmaf(cA62, k2b, fmaf(cA63, k3b, fmaf(cA64, k4b, cA65 * k5b)))); break;
                    default: sum0 = fmaf(cB1, k1a, fmaf(cB2, k2a, fmaf(cB3, k3a, fmaf(cB4, k4a, fmaf(cB5, k5a, cB6 * k6a)))));
                             sum1 = fmaf(cB1, k1b, fmaf(cB2, k2b, fmaf(cB3, k3b, fmaf(cB4, k4b, fmaf(cB5, k5b, cB6 * k6b))))); break;
                }
                float arg0 = fmaf(h, sum0, y0);
                float arg1 = fmaf(h, sum1, y1);
                if (st == 7) { y50 = arg0; y51 = arg1; }
                argw(arg0, arg1);
            }
            float kv0 = 0.f, kv1 = 0.f;
            eval(kv0, kv1);
            if (wave < 4) {
                switch (st) {
                    case 2: k2a = kv0; k2b = kv1; break;
                    case 3: k3a = kv0; k3b = kv1; break;
                    case 4: k4a = kv0; k4b = kv1; break;
                    case 5: k5a = kv0; k5b = kv1; break;
                    case 6: k6a = kv0; k6b = kv1; break;
                    default: k7a = kv0; k7b = kv1; break;
                }
            }
        }

        // error norm: per-lane 2-dim partial -> wave partial -> LDS -> all
        float rr2 = 0.f;
        if (wave < 4) {
            float es0 = fmaf(cE1, k1a, fmaf(cE2, k2a, fmaf(cE3, k3a,
                        fmaf(cE4, k4a, fmaf(cE5, k5a, fmaf(cE6, k6a, cE7 * k7a))))));
            float es1 = fmaf(cE1, k1b, fmaf(cE2, k2b, fmaf(cE3, k3b,
                        fmaf(cE4, k4b, fmaf(cE5, k5b, fmaf(cE6, k6b, cE7 * k7b))))));
            float err0 = h * es0, err1 = h * es1;
            float sc0 = fmaf(1e-3f, fmaxf(fabsf(y0), fabsf(y50)), 1e-6f);
            float sc1 = fmaf(1e-3f, fmaxf(fabsf(y1), fabsf(y51)), 1e-6f);
            float r0 = err0 / sc0, r1 = err1 / sc1;
            rr2 = fmaf(r0, r0, r1 * r1);
        }
        rr2 += __shfl_xor(rr2, 16, 64);   // sum quad bit0
        rr2 += __shfl_xor(rr2, 32, 64);   // sum quad bit1
        rr2 = fold8(rr2);                 // sum esel halves (symmetric, no select)
        if (wave < 4 && lane < 8) rrP[wave * 8 + lane] = rr2;  // lane = elem
        __syncthreads();
        float rs = ((rrP[e] + rrP[8 + e]) + rrP[16 + e]) + rrP[24 + e];
        float en = sqrtf(rs * (1.0f / 64.0f));

        bool accept = (en <= 1.0f) && aliveE;
        float fac = 0.9f * exp2f(-0.2f * log2f(fmaxf(en, 1e-10f)));
        fac = fminf(fmaxf(fac, 0.2f), 10.0f);

        if (wave < 4 && accept) { y0 = y50; y1 = y51; k1a = k7a; k1b = k7b; }  // FSAL
        if (aliveE) dt = dt_c * fac;      // dt update uses clamped dt_c (ref order)
        if (accept) {
            t += dt_c;
            if (t >= tEnd - 1e-8f) {      // segment crossing: write + advance
                if (wave < 4) {
                    float2 yy; yy.x = y0; yy.y = y1;
                    *(float2*)(out + (elemIdx * NSEG + (segE - 1)) * 64 + d0) = yy;
                }
                t = tEnd;                 // exact reset (ref: t = t1 - 1 next seg)
                segE += 1;
                if (segE > NSEG) aliveE = false;
            }
        }
        if (__all(!aliveE)) break;
    }
}

extern "C" void kernel_launch(void* const* d_in, const int* in_sizes, int n_in,
                              void* d_out, int out_size, void* d_ws, size_t ws_size,
                              hipStream_t stream) {
    const float* history = (const float*)d_in[0];
    const float* W1 = (const float*)d_in[1];
    const float* b1 = (const float*)d_in[2];
    const float* W2 = (const float*)d_in[3];
    const float* b2 = (const float*)d_in[4];
    const float* W3 = (const float*)d_in[5];
    const float* b3 = (const float*)d_in[6];
    float* out = (float*)d_out;

    ode_kernel<<<dim3(NB / 8), dim3(512), 0, stream>>>(history, W1, b1, W2, b2, W3, b3, out);
}